// Round 1
// baseline (278.273 us; speedup 1.0000x reference)
//
#include <hip/hip_runtime.h>

#define Bn 4
#define Ln 4096
#define Cn 128
#define DIn 256
#define NCn 64
#define LCn 64
#define ROWS (Bn*Ln)

__device__ __forceinline__ float siluf(float x){ return x / (1.f + __expf(-x)); }
__device__ __forceinline__ float softplusf(float x){ return fmaxf(x,0.f) + __logf(1.f + __expf(-fabsf(x))); }

// ---------------- G1: xz[dir] = (dir ? reversed xs : xs) @ W_in[dir] ----------------
// A read straight from x (B,C,L) layout -> k-major staging is coalesced.
// M=16384 N=512 K=128. Tile 128x128, 256 thr, 8x8 per thread.
__global__ __launch_bounds__(256) void k_g1(const float* __restrict__ x,
    const float* __restrict__ Wf, const float* __restrict__ Wb,
    float* __restrict__ xzf, float* __restrict__ xzb)
{
  const int dir = blockIdx.z;
  const float* __restrict__ W = dir ? Wb : Wf;
  float* __restrict__ xz = dir ? xzb : xzf;
  const int row0 = blockIdx.x * 128;
  const int n0 = blockIdx.y * 128;
  const int b = row0 >> 12;
  const int t0 = row0 & (Ln-1);
  const float* __restrict__ xb = x + (size_t)b * Cn * Ln;
  __shared__ float As[16][128];
  __shared__ float Bs[16][128];
  const int tid = threadIdx.x;
  const int tx = tid & 15, ty = tid >> 4;
  float acc[8][8];
  #pragma unroll
  for (int i=0;i<8;++i)
    #pragma unroll
    for (int j=0;j<8;++j) acc[i][j]=0.f;

  for (int k0 = 0; k0 < 128; k0 += 16) {
    #pragma unroll
    for (int jj = 0; jj < 8; ++jj) {
      int idx = tid + jj*256;
      int k = idx >> 7, i = idx & 127;
      int t = t0 + i;
      int ts = dir ? (Ln-1-t) : t;
      As[k][i] = xb[(size_t)(k0+k)*Ln + ts];
    }
    #pragma unroll
    for (int jj = 0; jj < 8; ++jj) {
      int idx = tid + jj*256;
      int k = idx >> 7, n = idx & 127;
      Bs[k][n] = W[(size_t)(k0+k)*512 + n0 + n];
    }
    __syncthreads();
    #pragma unroll
    for (int kk = 0; kk < 16; ++kk) {
      float a[8], bv[8];
      *(float4*)&a[0] = *(const float4*)&As[kk][ty*8];
      *(float4*)&a[4] = *(const float4*)&As[kk][ty*8+4];
      *(float4*)&bv[0] = *(const float4*)&Bs[kk][tx*8];
      *(float4*)&bv[4] = *(const float4*)&Bs[kk][tx*8+4];
      #pragma unroll
      for (int i=0;i<8;++i)
        #pragma unroll
        for (int j=0;j<8;++j) acc[i][j] = fmaf(a[i], bv[j], acc[i][j]);
    }
    __syncthreads();
  }
  #pragma unroll
  for (int i=0;i<8;++i) {
    float* p = xz + (size_t)(row0 + ty*8 + i)*512 + n0 + tx*8;
    *(float4*)p = *(float4*)&acc[i][0];
    *(float4*)(p+4) = *(float4*)&acc[i][4];
  }
}

// ---------------- conv: xc = silu(xp[t-1]*w0 + xp[t]*w1 + cb) ----------------
__global__ __launch_bounds__(256) void k_conv(
    const float* __restrict__ xzf, const float* __restrict__ xzb,
    const float* __restrict__ cwf, const float* __restrict__ cwb,
    const float* __restrict__ cbf, const float* __restrict__ cbb,
    float* __restrict__ xcf, float* __restrict__ xcb)
{
  const int dir = blockIdx.y;
  const float* __restrict__ xz = dir ? xzb : xzf;
  const float* __restrict__ cw = dir ? cwb : cwf;
  const float* __restrict__ cb = dir ? cbb : cbf;
  float* __restrict__ xc = dir ? xcb : xcf;
  const int n4 = ROWS * 64;
  for (int idx4 = blockIdx.x*256 + threadIdx.x; idx4 < n4; idx4 += gridDim.x*256) {
    int row = idx4 >> 6;
    int d0 = (idx4 & 63) * 4;
    float4 cur = *(const float4*)(xz + (size_t)row*512 + d0);
    float4 prev = make_float4(0.f,0.f,0.f,0.f);
    if (row & (Ln-1)) prev = *(const float4*)(xz + (size_t)(row-1)*512 + d0);
    float4 cwA = *(const float4*)(cw + d0*2);
    float4 cwB = *(const float4*)(cw + d0*2 + 4);
    float4 cb4 = *(const float4*)(cb + d0);
    float4 r;
    r.x = siluf(fmaf(prev.x,cwA.x, fmaf(cur.x,cwA.y, cb4.x)));
    r.y = siluf(fmaf(prev.y,cwA.z, fmaf(cur.y,cwA.w, cb4.y)));
    r.z = siluf(fmaf(prev.z,cwB.x, fmaf(cur.z,cwB.y, cb4.z)));
    r.w = siluf(fmaf(prev.w,cwB.z, fmaf(cur.w,cwB.w, cb4.w)));
    *(float4*)(xc + (size_t)row*256 + d0) = r;
  }
}

// ---------------- G2: xdb = xc @ W_x  (M=16384 K=256 N=40 pad 64) ----------------
// Tile 128x64, 256 thr, 8x4 per thread. A staged k-major via float4 + scatter.
__global__ __launch_bounds__(256) void k_g2(
    const float* __restrict__ xcf, const float* __restrict__ xcb,
    const float* __restrict__ Wxf, const float* __restrict__ Wxb,
    float* __restrict__ xdbf, float* __restrict__ xdbb)
{
  const int dir = blockIdx.z;
  const float* __restrict__ xc = dir ? xcb : xcf;
  const float* __restrict__ Wx = dir ? Wxb : Wxf;
  float* __restrict__ xdb = dir ? xdbb : xdbf;
  const int row0 = blockIdx.x * 128;
  __shared__ float As[16][132];
  __shared__ float Bs[16][64];
  const int tid = threadIdx.x;
  const int tx = tid & 15, ty = tid >> 4;
  float acc[8][4];
  #pragma unroll
  for (int i=0;i<8;++i)
    #pragma unroll
    for (int j=0;j<4;++j) acc[i][j]=0.f;

  for (int k0 = 0; k0 < 256; k0 += 16) {
    #pragma unroll
    for (int j = 0; j < 2; ++j) {
      int f = tid + j*256;
      int r = f >> 2, v = f & 3;
      float4 t4 = *(const float4*)(xc + (size_t)(row0+r)*256 + k0 + v*4);
      As[v*4+0][r]=t4.x; As[v*4+1][r]=t4.y; As[v*4+2][r]=t4.z; As[v*4+3][r]=t4.w;
    }
    #pragma unroll
    for (int j = 0; j < 4; ++j) {
      int idx = tid + j*256;
      int k = idx >> 6, n = idx & 63;
      Bs[k][n] = (n < 40) ? Wx[(size_t)(k0+k)*40 + n] : 0.f;
    }
    __syncthreads();
    #pragma unroll
    for (int kk=0;kk<16;++kk) {
      float a[8], bv[4];
      *(float4*)&a[0] = *(const float4*)&As[kk][ty*8];
      *(float4*)&a[4] = *(const float4*)&As[kk][ty*8+4];
      *(float4*)&bv[0] = *(const float4*)&Bs[kk][tx*4];
      #pragma unroll
      for (int i=0;i<8;++i)
        #pragma unroll
        for (int j=0;j<4;++j) acc[i][j] = fmaf(a[i], bv[j], acc[i][j]);
    }
    __syncthreads();
  }
  if (tx < 10) {
    #pragma unroll
    for (int i=0;i<8;++i)
      #pragma unroll
      for (int j=0;j<4;++j)
        xdb[(size_t)(row0+ty*8+i)*40 + tx*4 + j] = acc[i][j];
  }
}

// ---------------- pass1: per-chunk local scan from h=0; store h_end + sum(dt) ----------------
__global__ __launch_bounds__(256) void k_pass1(
    const float* __restrict__ xdbf, const float* __restrict__ xdbb,
    const float* __restrict__ xcf, const float* __restrict__ xcb,
    const float* __restrict__ Wdtf, const float* __restrict__ Wdtb,
    const float* __restrict__ bdtf, const float* __restrict__ bdtb,
    const float* __restrict__ Alf, const float* __restrict__ Alb,
    float* __restrict__ sdtf, float* __restrict__ sdtb,
    float* __restrict__ hkf, float* __restrict__ hkb)
{
  const int dir = blockIdx.y;
  const float* __restrict__ xdb = dir ? xdbb : xdbf;
  const float* __restrict__ xc  = dir ? xcb  : xcf;
  const float* __restrict__ Wdt = dir ? Wdtb : Wdtf;
  const float* __restrict__ bdt = dir ? bdtb : bdtf;
  const float* __restrict__ Al  = dir ? Alb  : Alf;
  float* __restrict__ sdt = dir ? sdtb : sdtf;
  float* __restrict__ hk  = dir ? hkb  : hkf;
  const int b = blockIdx.x >> 6, c = blockIdx.x & 63;
  const int t0 = c * LCn;
  __shared__ float S[LCn][24];   // [t][0..7]=dt_r, [8..23]=Bc
  const int tid = threadIdx.x;
  #pragma unroll
  for (int j=0;j<6;++j) {
    int idx = tid + j*256;
    int t = idx/24, jj = idx - t*24;
    S[t][jj] = xdb[(size_t)(b*Ln + t0 + t)*40 + jj];
  }
  const int d = tid;
  float Areg[16];
  #pragma unroll
  for (int s=0;s<16;++s) Areg[s] = -__expf(Al[d*16+s]);
  float wdt[8];
  #pragma unroll
  for (int j=0;j<8;++j) wdt[j] = Wdt[j*256+d];
  const float bd = bdt[d];
  float h[16];
  #pragma unroll
  for (int s=0;s<16;++s) h[s]=0.f;
  float sacc = 0.f;
  __syncthreads();
  for (int t=0;t<LCn;++t) {
    float dtv = bd;
    #pragma unroll
    for (int j=0;j<8;++j) dtv = fmaf(S[t][j], wdt[j], dtv);
    dtv = softplusf(dtv);
    float xv = xc[(size_t)(b*Ln + t0 + t)*256 + d];
    float u = dtv * xv;
    sacc += dtv;
    #pragma unroll
    for (int s=0;s<16;++s)
      h[s] = fmaf(__expf(dtv*Areg[s]), h[s], u*S[t][8+s]);
  }
  sdt[(size_t)(b*NCn + c)*256 + d] = sacc;
  #pragma unroll
  for (int s=0;s<16;++s)
    hk[(size_t)((b*NCn + c)*16 + s)*256 + d] = h[s];
}

// ---------------- pass2: inter-chunk recurrence; hk becomes h_in per chunk (in place) -------
__global__ __launch_bounds__(256) void k_pass2(
    const float* __restrict__ Alf, const float* __restrict__ Alb,
    const float* __restrict__ sdtf, const float* __restrict__ sdtb,
    float* __restrict__ hkf, float* __restrict__ hkb)
{
  const int dir = blockIdx.y;
  const float* __restrict__ Al  = dir ? Alb : Alf;
  const float* __restrict__ sdt = dir ? sdtb : sdtf;
  float* __restrict__ hk = dir ? hkb : hkf;
  int g = blockIdx.x*256 + threadIdx.x;
  int d = g & 255, s = (g >> 8) & 15, b = g >> 12;
  float Ad = -__expf(Al[d*16+s]);
  float h = 0.f;
  for (int c=0;c<NCn;++c) {
    int bc = b*NCn + c;
    float sd = sdt[(size_t)bc*256 + d];
    size_t hi = (size_t)(bc*16 + s)*256 + d;
    float he = hk[hi];
    hk[hi] = h;                       // carry-in for chunk c
    h = fmaf(__expf(Ad*sd), h, he);   // chunk transform: P*h + h_end_local
  }
}

// ---------------- pass3: replay chunk from carry-in; y + D*xc, gate by silu(z); in-place in xz z-half
__global__ __launch_bounds__(256) void k_pass3(
    const float* __restrict__ xdbf, const float* __restrict__ xdbb,
    const float* __restrict__ xcf, const float* __restrict__ xcb,
    const float* __restrict__ Wdtf, const float* __restrict__ Wdtb,
    const float* __restrict__ bdtf, const float* __restrict__ bdtb,
    const float* __restrict__ Alf, const float* __restrict__ Alb,
    const float* __restrict__ Dvf, const float* __restrict__ Dvb,
    const float* __restrict__ hkf, const float* __restrict__ hkb,
    float* __restrict__ xzf, float* __restrict__ xzb)
{
  const int dir = blockIdx.y;
  const float* __restrict__ xdb = dir ? xdbb : xdbf;
  const float* __restrict__ xc  = dir ? xcb  : xcf;
  const float* __restrict__ Wdt = dir ? Wdtb : Wdtf;
  const float* __restrict__ bdt = dir ? bdtb : bdtf;
  const float* __restrict__ Al  = dir ? Alb  : Alf;
  const float* __restrict__ Dv  = dir ? Dvb  : Dvf;
  const float* __restrict__ hk  = dir ? hkb  : hkf;
  float* __restrict__ xz = dir ? xzb : xzf;
  const int b = blockIdx.x >> 6, c = blockIdx.x & 63;
  const int t0 = c * LCn;
  __shared__ float S[LCn][40];  // [0..7]=dt_r [8..23]=B [24..39]=C
  const int tid = threadIdx.x;
  #pragma unroll
  for (int j=0;j<10;++j) {
    int idx = tid + j*256;
    int t = idx/40, jj = idx - t*40;
    S[t][jj] = xdb[(size_t)(b*Ln + t0 + t)*40 + jj];
  }
  const int d = tid;
  float Areg[16];
  #pragma unroll
  for (int s=0;s<16;++s) Areg[s] = -__expf(Al[d*16+s]);
  float wdt[8];
  #pragma unroll
  for (int j=0;j<8;++j) wdt[j] = Wdt[j*256+d];
  const float bd = bdt[d];
  const float Dd = Dv[d];
  float h[16];
  #pragma unroll
  for (int s=0;s<16;++s) h[s] = hk[(size_t)((b*NCn + c)*16 + s)*256 + d];
  __syncthreads();
  for (int t=0;t<LCn;++t) {
    float dtv = bd;
    #pragma unroll
    for (int j=0;j<8;++j) dtv = fmaf(S[t][j], wdt[j], dtv);
    dtv = softplusf(dtv);
    size_t rowi = (size_t)(b*Ln + t0 + t);
    float xv = xc[rowi*256 + d];
    float u = dtv * xv;
    float y = 0.f;
    #pragma unroll
    for (int s=0;s<16;++s) {
      h[s] = fmaf(__expf(dtv*Areg[s]), h[s], u*S[t][8+s]);
      y = fmaf(h[s], S[t][24+s], y);
    }
    y = fmaf(Dd, xv, y);
    float zv = xz[rowi*512 + 256 + d];
    xz[rowi*512 + 256 + d] = y * siluf(zv);
  }
}

// ---------------- Gout: ysum = sum_dir ygate[dir](row-mapped) @ W_out[dir] ----------------
// Tile 64x128, 256 thr, 4x8 per thread. K=256 per dir.
__global__ __launch_bounds__(256) void k_gout(
    const float* __restrict__ xzf, const float* __restrict__ xzb,
    const float* __restrict__ Wof, const float* __restrict__ Wob,
    float* __restrict__ ysum)
{
  const int row0 = blockIdx.x * 64;
  const int b = row0 >> 12;
  const int l0 = row0 & (Ln-1);
  __shared__ float As[16][68];
  __shared__ float Bs[16][128];
  const int tid = threadIdx.x;
  const int tx = tid & 15, ty = tid >> 4;
  float acc[4][8];
  #pragma unroll
  for (int i=0;i<4;++i)
    #pragma unroll
    for (int j=0;j<8;++j) acc[i][j]=0.f;

  for (int dir=0; dir<2; ++dir) {
    const float* __restrict__ xz = dir ? xzb : xzf;
    const float* __restrict__ Wo = dir ? Wob : Wof;
    for (int k0=0;k0<256;k0+=16) {
      {
        int r = tid >> 2, v = tid & 3;
        int lr = l0 + r;
        size_t src = (size_t)b*Ln + (dir ? (Ln-1-lr) : lr);
        float4 t4 = *(const float4*)(xz + src*512 + 256 + k0 + v*4);
        As[v*4+0][r]=t4.x; As[v*4+1][r]=t4.y; As[v*4+2][r]=t4.z; As[v*4+3][r]=t4.w;
      }
      #pragma unroll
      for (int j=0;j<8;++j) {
        int idx = tid + j*256;
        int k = idx >> 7, n = idx & 127;
        Bs[k][n] = Wo[(size_t)(k0+k)*128 + n];
      }
      __syncthreads();
      #pragma unroll
      for (int kk=0;kk<16;++kk) {
        float a[4], bv[8];
        *(float4*)&a[0] = *(const float4*)&As[kk][ty*4];
        *(float4*)&bv[0] = *(const float4*)&Bs[kk][tx*8];
        *(float4*)&bv[4] = *(const float4*)&Bs[kk][tx*8+4];
        #pragma unroll
        for (int i=0;i<4;++i)
          #pragma unroll
          for (int j=0;j<8;++j) acc[i][j] = fmaf(a[i], bv[j], acc[i][j]);
      }
      __syncthreads();
    }
  }
  #pragma unroll
  for (int i=0;i<4;++i) {
    float* p = ysum + (size_t)(row0 + ty*4 + i)*128 + tx*8;
    *(float4*)p = *(float4*)&acc[i][0];
    *(float4*)(p+4) = *(float4*)&acc[i][4];
  }
}

// ---------------- GroupNorm stats (partials) ----------------
__global__ __launch_bounds__(256) void k_gnstat(const float* __restrict__ ysum, float* __restrict__ part)
{
  const int bg = blockIdx.x >> 4;
  const int blk = blockIdx.x & 15;
  const int b = bg >> 2, g = bg & 3;
  float s=0.f, q=0.f;
  #pragma unroll
  for (int i=0;i<8;++i) {
    int e4 = blk*2048 + threadIdx.x + i*256;
    int l = e4 >> 3, c4 = e4 & 7;
    float4 v = *(const float4*)(ysum + (size_t)(b*Ln + l)*128 + g*32 + c4*4);
    s += v.x+v.y+v.z+v.w;
    q = fmaf(v.x,v.x, fmaf(v.y,v.y, fmaf(v.z,v.z, fmaf(v.w,v.w, q))));
  }
  __shared__ float rs[256], rq[256];
  rs[threadIdx.x]=s; rq[threadIdx.x]=q;
  __syncthreads();
  for (int off=128; off>0; off>>=1) {
    if (threadIdx.x < off) { rs[threadIdx.x]+=rs[threadIdx.x+off]; rq[threadIdx.x]+=rq[threadIdx.x+off]; }
    __syncthreads();
  }
  if (threadIdx.x==0) { part[blockIdx.x*2]=rs[0]; part[blockIdx.x*2+1]=rq[0]; }
}

__global__ void k_gnred(const float* __restrict__ part, float* __restrict__ mr)
{
  int t = threadIdx.x;
  if (t < 16) {
    float s=0.f,q=0.f;
    for (int k=0;k<16;++k){ s+=part[(t*16+k)*2]; q+=part[(t*16+k)*2+1]; }
    const float inv = 1.f/131072.f;
    float mean = s*inv;
    float var = fmaf(-mean, mean, q*inv);
    mr[t*2] = mean;
    mr[t*2+1] = rsqrtf(var + 1e-5f);
  }
}

// ---------------- GN apply + silu + residual, (B,L,C)->(B,C,L) via LDS transpose ----------
__global__ __launch_bounds__(256) void k_gnapply(const float* __restrict__ ysum,
    const float* __restrict__ mr, const float* __restrict__ gamma, const float* __restrict__ beta,
    const float* __restrict__ x, float* __restrict__ out)
{
  const int b = blockIdx.x >> 6;
  const int l0 = (blockIdx.x & 63) * 64;
  __shared__ float T[64][132];
  const int tid = threadIdx.x;
  #pragma unroll
  for (int j=0;j<8;++j) {
    int f = tid + j*256;
    int l = f >> 5, c4 = f & 31;
    *(float4*)&T[l][c4*4] = *(const float4*)(ysum + (size_t)(b*Ln + l0 + l)*128 + c4*4);
  }
  __syncthreads();
  #pragma unroll
  for (int j=0;j<8;++j) {
    int f = tid + j*256;
    int c = f >> 4, lv = f & 15;
    int bg = b*4 + (c>>5);
    float mean = mr[bg*2];
    float rstd = mr[bg*2+1];
    float gam = gamma[c], bet = beta[c];
    size_t base = (size_t)(b*Cn + c)*Ln + l0 + lv*4;
    float4 xv = *(const float4*)(x + base);
    float4 r;
    r.x = siluf(fmaf((T[lv*4+0][c]-mean)*rstd, gam, bet)) + xv.x;
    r.y = siluf(fmaf((T[lv*4+1][c]-mean)*rstd, gam, bet)) + xv.y;
    r.z = siluf(fmaf((T[lv*4+2][c]-mean)*rstd, gam, bet)) + xv.z;
    r.w = siluf(fmaf((T[lv*4+3][c]-mean)*rstd, gam, bet)) + xv.w;
    *(float4*)(out + base) = r;
  }
}

extern "C" void kernel_launch(void* const* d_in, const int* in_sizes, int n_in,
                              void* d_out, int out_size, void* d_ws, size_t ws_size,
                              hipStream_t stream) {
  const float* x      = (const float*)d_in[0];
  const float* W_in_f = (const float*)d_in[1];
  const float* cw_f   = (const float*)d_in[2];
  const float* cb_f   = (const float*)d_in[3];
  const float* Wx_f   = (const float*)d_in[4];
  const float* Wdt_f  = (const float*)d_in[5];
  const float* bdt_f  = (const float*)d_in[6];
  const float* Al_f   = (const float*)d_in[7];
  const float* D_f    = (const float*)d_in[8];
  const float* Wo_f   = (const float*)d_in[9];
  const float* W_in_b = (const float*)d_in[10];
  const float* cw_b   = (const float*)d_in[11];
  const float* cb_b   = (const float*)d_in[12];
  const float* Wx_b   = (const float*)d_in[13];
  const float* Wdt_b  = (const float*)d_in[14];
  const float* bdt_b  = (const float*)d_in[15];
  const float* Al_b   = (const float*)d_in[16];
  const float* D_b    = (const float*)d_in[17];
  const float* Wo_b   = (const float*)d_in[18];
  const float* gamma  = (const float*)d_in[19];
  const float* beta   = (const float*)d_in[20];
  float* out = (float*)d_out;

  float* w = (float*)d_ws;
  size_t o = 0;
  float* xz0  = w + o; o += (size_t)ROWS*512;
  float* xz1  = w + o; o += (size_t)ROWS*512;
  float* xc0  = w + o; o += (size_t)ROWS*256;
  float* xc1  = w + o; o += (size_t)ROWS*256;
  float* xdb0 = w + o; o += (size_t)ROWS*40;
  float* xdb1 = w + o; o += (size_t)ROWS*40;
  float* sdt0 = w + o; o += (size_t)Bn*NCn*256;
  float* sdt1 = w + o; o += (size_t)Bn*NCn*256;
  float* hk0  = w + o; o += (size_t)Bn*NCn*16*256;
  float* hk1  = w + o; o += (size_t)Bn*NCn*16*256;
  float* ysum = w + o; o += (size_t)ROWS*128;
  float* part = w + o; o += 512;
  float* mr   = w + o; o += 32;
  if (ws_size < o*sizeof(float)) return;  // insufficient scratch: fail loudly via validation

  k_g1<<<dim3(ROWS/128, 4, 2), 256, 0, stream>>>(x, W_in_f, W_in_b, xz0, xz1);
  k_conv<<<dim3(1024, 2), 256, 0, stream>>>(xz0, xz1, cw_f, cw_b, cb_f, cb_b, xc0, xc1);
  k_g2<<<dim3(ROWS/128, 1, 2), 256, 0, stream>>>(xc0, xc1, Wx_f, Wx_b, xdb0, xdb1);
  k_pass1<<<dim3(Bn*NCn, 2), 256, 0, stream>>>(xdb0, xdb1, xc0, xc1, Wdt_f, Wdt_b,
                                               bdt_f, bdt_b, Al_f, Al_b, sdt0, sdt1, hk0, hk1);
  k_pass2<<<dim3(64, 2), 256, 0, stream>>>(Al_f, Al_b, sdt0, sdt1, hk0, hk1);
  k_pass3<<<dim3(Bn*NCn, 2), 256, 0, stream>>>(xdb0, xdb1, xc0, xc1, Wdt_f, Wdt_b,
                                               bdt_f, bdt_b, Al_f, Al_b, D_f, D_b,
                                               hk0, hk1, xz0, xz1);
  k_gout<<<dim3(ROWS/64), 256, 0, stream>>>(xz0, xz1, Wo_f, Wo_b, ysum);
  k_gnstat<<<dim3(256), 256, 0, stream>>>(ysum, part);
  k_gnred<<<dim3(1), 64, 0, stream>>>(part, mr);
  k_gnapply<<<dim3(256), 256, 0, stream>>>(ysum, mr, gamma, beta, x, out);
}

// Round 4
// 226.922 us; speedup vs baseline: 1.2263x; 1.2263x over previous
//
#include <hip/hip_runtime.h>

#define Bn 4
#define Ln 4096
#define Cn 128
#define DIn 256
#define NCn 64
#define LCn 64
#define ROWS (Bn*Ln)

typedef short s8v __attribute__((ext_vector_type(8)));
typedef short s4v __attribute__((ext_vector_type(4)));
typedef float f4v __attribute__((ext_vector_type(4)));

__device__ __forceinline__ float siluf(float x){ return x / (1.f + __expf(-x)); }
__device__ __forceinline__ float softplusf(float x){ return fmaxf(x,0.f) + __logf(1.f + __expf(-fabsf(x))); }

// split x into bf16 hi + bf16(residual): ~16-bit effective mantissa
__device__ __forceinline__ void splitbf(float x, short& h, short& l){
  uint u = __float_as_uint(x);
  uint hh = (u + 0x7fffu + ((u>>16)&1u)) >> 16;
  float hf = __uint_as_float(hh<<16);
  float r = x - hf;
  uint v = __float_as_uint(r);
  l = (short)((v + 0x7fffu + ((v>>16)&1u)) >> 16);
  h = (short)hh;
}

// LDS tile layout (per 128x32 operand tile, bf16): 8 subtiles of [16 rows][32 k],
// 512 shorts each. Within a row, k lives in 4 granules of 8 shorts; granule index
// is XOR-swizzled by ((row&15)>>1)&3 so wave-wide s8v fragment reads are ~2-way
// bank-aliased (free per m136). All LDS ops are compiler-visible (no inline asm).
__device__ __forceinline__ int tile_off(int r, int gran, int ghalf){
  return ((r>>4)<<9) + ((r&15)<<5) + (((gran ^ ((r>>1)&3)))<<3) + ghalf;
}

// ---------------- G1 (MFMA split-bf16): xz[dir] = (dir? rev xs : xs) @ W_in[dir] ----------------
// M=16384 N=512 K=128. Block tile 128x128, 4 waves (2x2), each 64x64, 16x16x32 MFMA.
__global__ __launch_bounds__(256) void k_g1(const float* __restrict__ x,
    const float* __restrict__ Wf, const float* __restrict__ Wb,
    float* __restrict__ xzf, float* __restrict__ xzb)
{
  const int dir = blockIdx.z;
  const float* __restrict__ W = dir ? Wb : Wf;
  float* __restrict__ xz = dir ? xzb : xzf;
  const int row0 = blockIdx.x * 128;
  const int n0 = blockIdx.y * 128;
  const int b = row0 >> 12;
  const int t0 = row0 & (Ln-1);
  const float* __restrict__ xb = x + (size_t)b * Cn * Ln;

  __shared__ short Ah[8*512], Al[8*512], Bh[8*512], Bl[8*512];

  const int tid = threadIdx.x;
  const int lane = tid & 63;
  const int wid = tid >> 6;
  const int wr = wid >> 1, wc = wid & 1;
  const int r16 = lane & 15, kg = lane >> 4;

  // staging: thread covers 4 consecutive positions (q) x 4 consecutive k (kq)
  const int q = tid & 31, kq = tid >> 5;
  const int kbase = 4*kq;
  const int g_true = kq >> 1;
  const int ghalf = (kq & 1) * 4;

  f4v acc[4][4];
  #pragma unroll
  for (int i=0;i<4;++i)
    #pragma unroll
    for (int j=0;j<4;++j) acc[i][j] = (f4v){0.f,0.f,0.f,0.f};

  for (int ks=0; ks<4; ++ks) {
    const int k0 = ks*32;
    if (ks) __syncthreads();
    // ---- stage A: A[r][k] = xs(t0+r)[k0+k]  (xs reversed for dir=1)
    {
      float4 va[4];
      if (dir==0) {
        #pragma unroll
        for (int kk=0;kk<4;++kk)
          va[kk] = *(const float4*)(xb + (size_t)(k0+kbase+kk)*Ln + t0 + 4*q);
      } else {
        #pragma unroll
        for (int kk=0;kk<4;++kk)
          va[kk] = *(const float4*)(xb + (size_t)(k0+kbase+kk)*Ln + (Ln-4 - t0 - 4*q));
      }
      #pragma unroll
      for (int e=0;e<4;++e) {
        int r = 4*q + e;
        int off = tile_off(r, g_true, ghalf);
        int c = dir ? (3-e) : e;
        s4v hv, lv;
        #pragma unroll
        for (int kk=0;kk<4;++kk) {
          float f = ((const float*)&va[kk])[c];
          short hh,ll; splitbf(f,hh,ll);
          hv[kk]=hh; lv[kk]=ll;
        }
        *(s4v*)&Ah[off] = hv;
        *(s4v*)&Al[off] = lv;
      }
    }
    // ---- stage B: B[n][k] = W[k0+k][n0+n]
    {
      float4 vb[4];
      #pragma unroll
      for (int kk=0;kk<4;++kk)
        vb[kk] = *(const float4*)(W + (size_t)(k0+kbase+kk)*512 + n0 + 4*q);
      #pragma unroll
      for (int e=0;e<4;++e) {
        int r = 4*q + e;
        int off = tile_off(r, g_true, ghalf);
        s4v hv, lv;
        #pragma unroll
        for (int kk=0;kk<4;++kk) {
          float f = ((const float*)&vb[kk])[e];
          short hh,ll; splitbf(f,hh,ll);
          hv[kk]=hh; lv[kk]=ll;
        }
        *(s4v*)&Bh[off] = hv;
        *(s4v*)&Bl[off] = lv;
      }
    }
    __syncthreads();
    // ---- fragment loads (plain b128, compiler-managed waits) ----
    const int gsh = ((kg ^ ((r16>>1)&3)) << 3);
    s8v fah[4], fal[4], fbh[4], fbl[4];
    #pragma unroll
    for (int m=0;m<4;++m) {
      int idx = (wr*4+m)*512 + r16*32 + gsh;
      fah[m] = *(const s8v*)&Ah[idx];
      fal[m] = *(const s8v*)&Al[idx];
    }
    #pragma unroll
    for (int n=0;n<4;++n) {
      int idx = (wc*4+n)*512 + r16*32 + gsh;
      fbh[n] = *(const s8v*)&Bh[idx];
      fbl[n] = *(const s8v*)&Bl[idx];
    }
    #pragma unroll
    for (int m=0;m<4;++m)
      #pragma unroll
      for (int n=0;n<4;++n) {
        acc[m][n] = __builtin_amdgcn_mfma_f32_16x16x32_bf16(fah[m], fbh[n], acc[m][n], 0,0,0);
        acc[m][n] = __builtin_amdgcn_mfma_f32_16x16x32_bf16(fah[m], fbl[n], acc[m][n], 0,0,0);
        acc[m][n] = __builtin_amdgcn_mfma_f32_16x16x32_bf16(fal[m], fbh[n], acc[m][n], 0,0,0);
      }
  }
  // ---- epilogue: D col=lane&15, row=4*(lane>>4)+v (m89/m91-verified)
  #pragma unroll
  for (int m=0;m<4;++m)
    #pragma unroll
    for (int v=0;v<4;++v) {
      int row = row0 + wr*64 + m*16 + kg*4 + v;
      float* p = xz + (size_t)row*512 + n0 + wc*64 + r16;
      #pragma unroll
      for (int n=0;n<4;++n) p[n*16] = acc[m][n][v];
    }
}

// ---------------- conv: xc = silu(xp[t-1]*w0 + xp[t]*w1 + cb) ----------------
__global__ __launch_bounds__(256) void k_conv(
    const float* __restrict__ xzf, const float* __restrict__ xzb,
    const float* __restrict__ cwf, const float* __restrict__ cwb,
    const float* __restrict__ cbf, const float* __restrict__ cbb,
    float* __restrict__ xcf, float* __restrict__ xcb)
{
  const int dir = blockIdx.y;
  const float* __restrict__ xz = dir ? xzb : xzf;
  const float* __restrict__ cw = dir ? cwb : cwf;
  const float* __restrict__ cb = dir ? cbb : cbf;
  float* __restrict__ xc = dir ? xcb : xcf;
  const int n4 = ROWS * 64;
  for (int idx4 = blockIdx.x*256 + threadIdx.x; idx4 < n4; idx4 += gridDim.x*256) {
    int row = idx4 >> 6;
    int d0 = (idx4 & 63) * 4;
    float4 cur = *(const float4*)(xz + (size_t)row*512 + d0);
    float4 prev = make_float4(0.f,0.f,0.f,0.f);
    if (row & (Ln-1)) prev = *(const float4*)(xz + (size_t)(row-1)*512 + d0);
    float4 cwA = *(const float4*)(cw + d0*2);
    float4 cwB = *(const float4*)(cw + d0*2 + 4);
    float4 cb4 = *(const float4*)(cb + d0);
    float4 r;
    r.x = siluf(fmaf(prev.x,cwA.x, fmaf(cur.x,cwA.y, cb4.x)));
    r.y = siluf(fmaf(prev.y,cwA.z, fmaf(cur.y,cwA.w, cb4.y)));
    r.z = siluf(fmaf(prev.z,cwB.x, fmaf(cur.z,cwB.y, cb4.z)));
    r.w = siluf(fmaf(prev.w,cwB.z, fmaf(cur.w,cwB.w, cb4.w)));
    *(float4*)(xc + (size_t)row*256 + d0) = r;
  }
}

// ---------------- G2: xdb = xc @ W_x  (M=16384 K=256 N=40 pad 64) ----------------
__global__ __launch_bounds__(256) void k_g2(
    const float* __restrict__ xcf, const float* __restrict__ xcb,
    const float* __restrict__ Wxf, const float* __restrict__ Wxb,
    float* __restrict__ xdbf, float* __restrict__ xdbb)
{
  const int dir = blockIdx.z;
  const float* __restrict__ xc = dir ? xcb : xcf;
  const float* __restrict__ Wx = dir ? Wxb : Wxf;
  float* __restrict__ xdb = dir ? xdbb : xdbf;
  const int row0 = blockIdx.x * 128;
  __shared__ float As[16][132];
  __shared__ float Bs[16][64];
  const int tid = threadIdx.x;
  const int tx = tid & 15, ty = tid >> 4;
  float acc[8][4];
  #pragma unroll
  for (int i=0;i<8;++i)
    #pragma unroll
    for (int j=0;j<4;++j) acc[i][j]=0.f;

  for (int k0 = 0; k0 < 256; k0 += 16) {
    #pragma unroll
    for (int j = 0; j < 2; ++j) {
      int f = tid + j*256;
      int r = f >> 2, v = f & 3;
      float4 t4 = *(const float4*)(xc + (size_t)(row0+r)*256 + k0 + v*4);
      As[v*4+0][r]=t4.x; As[v*4+1][r]=t4.y; As[v*4+2][r]=t4.z; As[v*4+3][r]=t4.w;
    }
    #pragma unroll
    for (int j = 0; j < 4; ++j) {
      int idx = tid + j*256;
      int k = idx >> 6, n = idx & 63;
      Bs[k][n] = (n < 40) ? Wx[(size_t)(k0+k)*40 + n] : 0.f;
    }
    __syncthreads();
    #pragma unroll
    for (int kk=0;kk<16;++kk) {
      float a[8], bv[4];
      *(float4*)&a[0] = *(const float4*)&As[kk][ty*8];
      *(float4*)&a[4] = *(const float4*)&As[kk][ty*8+4];
      *(float4*)&bv[0] = *(const float4*)&Bs[kk][tx*4];
      #pragma unroll
      for (int i=0;i<8;++i)
        #pragma unroll
        for (int j=0;j<4;++j) acc[i][j] = fmaf(a[i], bv[j], acc[i][j]);
    }
    __syncthreads();
  }
  if (tx < 10) {
    #pragma unroll
    for (int i=0;i<8;++i)
      #pragma unroll
      for (int j=0;j<4;++j)
        xdb[(size_t)(row0+ty*8+i)*40 + tx*4 + j] = acc[i][j];
  }
}

// ---------------- pass1: per-chunk local scan from h=0; store h_end + sum(dt) ----------------
__global__ __launch_bounds__(256) void k_pass1(
    const float* __restrict__ xdbf, const float* __restrict__ xdbb,
    const float* __restrict__ xcf, const float* __restrict__ xcb,
    const float* __restrict__ Wdtf, const float* __restrict__ Wdtb,
    const float* __restrict__ bdtf, const float* __restrict__ bdtb,
    const float* __restrict__ Alf, const float* __restrict__ Alb,
    float* __restrict__ sdtf, float* __restrict__ sdtb,
    float* __restrict__ hkf, float* __restrict__ hkb)
{
  const int dir = blockIdx.y;
  const float* __restrict__ xdb = dir ? xdbb : xdbf;
  const float* __restrict__ xc  = dir ? xcb  : xcf;
  const float* __restrict__ Wdt = dir ? Wdtb : Wdtf;
  const float* __restrict__ bdt = dir ? bdtb : bdtf;
  const float* __restrict__ Al  = dir ? Alb  : Alf;
  float* __restrict__ sdt = dir ? sdtb : sdtf;
  float* __restrict__ hk  = dir ? hkb  : hkf;
  const int b = blockIdx.x >> 6, c = blockIdx.x & 63;
  const int t0 = c * LCn;
  __shared__ float S[LCn][24];
  const int tid = threadIdx.x;
  #pragma unroll
  for (int j=0;j<6;++j) {
    int idx = tid + j*256;
    int t = idx/24, jj = idx - t*24;
    S[t][jj] = xdb[(size_t)(b*Ln + t0 + t)*40 + jj];
  }
  const int d = tid;
  float Areg[16];
  #pragma unroll
  for (int s=0;s<16;++s) Areg[s] = -__expf(Al[d*16+s]);
  float wdt[8];
  #pragma unroll
  for (int j=0;j<8;++j) wdt[j] = Wdt[j*256+d];
  const float bd = bdt[d];
  float h[16];
  #pragma unroll
  for (int s=0;s<16;++s) h[s]=0.f;
  float sacc = 0.f;
  __syncthreads();
  for (int t=0;t<LCn;++t) {
    float dtv = bd;
    #pragma unroll
    for (int j=0;j<8;++j) dtv = fmaf(S[t][j], wdt[j], dtv);
    dtv = softplusf(dtv);
    float xv = xc[(size_t)(b*Ln + t0 + t)*256 + d];
    float u = dtv * xv;
    sacc += dtv;
    #pragma unroll
    for (int s=0;s<16;++s)
      h[s] = fmaf(__expf(dtv*Areg[s]), h[s], u*S[t][8+s]);
  }
  sdt[(size_t)(b*NCn + c)*256 + d] = sacc;
  #pragma unroll
  for (int s=0;s<16;++s)
    hk[(size_t)((b*NCn + c)*16 + s)*256 + d] = h[s];
}

// ---------------- pass2: inter-chunk recurrence ----------------
__global__ __launch_bounds__(256) void k_pass2(
    const float* __restrict__ Alf, const float* __restrict__ Alb,
    const float* __restrict__ sdtf, const float* __restrict__ sdtb,
    float* __restrict__ hkf, float* __restrict__ hkb)
{
  const int dir = blockIdx.y;
  const float* __restrict__ Al  = dir ? Alb : Alf;
  const float* __restrict__ sdt = dir ? sdtb : sdtf;
  float* __restrict__ hk = dir ? hkb : hkf;
  int g = blockIdx.x*256 + threadIdx.x;
  int d = g & 255, s = (g >> 8) & 15, b = g >> 12;
  float Ad = -__expf(Al[d*16+s]);
  float h = 0.f;
  for (int c=0;c<NCn;++c) {
    int bc = b*NCn + c;
    float sd = sdt[(size_t)bc*256 + d];
    size_t hi = (size_t)(bc*16 + s)*256 + d;
    float he = hk[hi];
    hk[hi] = h;
    h = fmaf(__expf(Ad*sd), h, he);
  }
}

// ---------------- pass3: replay chunk; y + D*xc, gate silu(z); in-place in xz z-half ----------------
__global__ __launch_bounds__(256) void k_pass3(
    const float* __restrict__ xdbf, const float* __restrict__ xdbb,
    const float* __restrict__ xcf, const float* __restrict__ xcb,
    const float* __restrict__ Wdtf, const float* __restrict__ Wdtb,
    const float* __restrict__ bdtf, const float* __restrict__ bdtb,
    const float* __restrict__ Alf, const float* __restrict__ Alb,
    const float* __restrict__ Dvf, const float* __restrict__ Dvb,
    const float* __restrict__ hkf, const float* __restrict__ hkb,
    float* __restrict__ xzf, float* __restrict__ xzb)
{
  const int dir = blockIdx.y;
  const float* __restrict__ xdb = dir ? xdbb : xdbf;
  const float* __restrict__ xc  = dir ? xcb  : xcf;
  const float* __restrict__ Wdt = dir ? Wdtb : Wdtf;
  const float* __restrict__ bdt = dir ? bdtb : bdtf;
  const float* __restrict__ Al  = dir ? Alb  : Alf;
  const float* __restrict__ Dv  = dir ? Dvb  : Dvf;
  const float* __restrict__ hk  = dir ? hkb  : hkf;
  float* __restrict__ xz = dir ? xzb : xzf;
  const int b = blockIdx.x >> 6, c = blockIdx.x & 63;
  const int t0 = c * LCn;
  __shared__ float S[LCn][40];
  const int tid = threadIdx.x;
  #pragma unroll
  for (int j=0;j<10;++j) {
    int idx = tid + j*256;
    int t = idx/40, jj = idx - t*40;
    S[t][jj] = xdb[(size_t)(b*Ln + t0 + t)*40 + jj];
  }
  const int d = tid;
  float Areg[16];
  #pragma unroll
  for (int s=0;s<16;++s) Areg[s] = -__expf(Al[d*16+s]);
  float wdt[8];
  #pragma unroll
  for (int j=0;j<8;++j) wdt[j] = Wdt[j*256+d];
  const float bd = bdt[d];
  const float Dd = Dv[d];
  float h[16];
  #pragma unroll
  for (int s=0;s<16;++s) h[s] = hk[(size_t)((b*NCn + c)*16 + s)*256 + d];
  __syncthreads();
  for (int t=0;t<LCn;++t) {
    float dtv = bd;
    #pragma unroll
    for (int j=0;j<8;++j) dtv = fmaf(S[t][j], wdt[j], dtv);
    dtv = softplusf(dtv);
    size_t rowi = (size_t)(b*Ln + t0 + t);
    float xv = xc[rowi*256 + d];
    float u = dtv * xv;
    float y = 0.f;
    #pragma unroll
    for (int s=0;s<16;++s) {
      h[s] = fmaf(__expf(dtv*Areg[s]), h[s], u*S[t][8+s]);
      y = fmaf(h[s], S[t][24+s], y);
    }
    y = fmaf(Dd, xv, y);
    float zv = xz[rowi*512 + 256 + d];
    xz[rowi*512 + 256 + d] = y * siluf(zv);
  }
}

// ---------------- Gout (MFMA split-bf16): ysum = sum_dir ygate[dir] @ W_out[dir] ----------------
// M=16384 N=128, K=2x256 (dir-concatenated). Block 128x128, 4 waves 2x2, 16 ksteps.
__global__ __launch_bounds__(256) void k_gout(
    const float* __restrict__ xzf, const float* __restrict__ xzb,
    const float* __restrict__ Wof, const float* __restrict__ Wob,
    float* __restrict__ ysum)
{
  const int row0 = blockIdx.x * 128;
  const int b = row0 >> 12;
  const int l0 = row0 & (Ln-1);

  __shared__ short Ah[8*512], Al[8*512], Bh[8*512], Bl[8*512];

  const int tid = threadIdx.x;
  const int lane = tid & 63;
  const int wid = tid >> 6;
  const int wr = wid >> 1, wc = wid & 1;
  const int r16 = lane & 15, kg = lane >> 4;

  // A staging mapping: r = tid>>1 (0..127), kseg = (tid&1)*16 (k-contiguous source)
  const int ar = tid >> 1;
  const int kseg = (tid & 1) * 16;
  const int arl = ar & 15, amt = ar >> 4;
  const int asw = (arl >> 1) & 3;
  // B staging mapping: 4 cols (q) x 4 k (kq)
  const int q = tid & 31, kq = tid >> 5;
  const int kbase = 4*kq;
  const int g_true = kq >> 1;
  const int ghalf = (kq & 1) * 4;

  f4v acc[4][4];
  #pragma unroll
  for (int i=0;i<4;++i)
    #pragma unroll
    for (int j=0;j<4;++j) acc[i][j] = (f4v){0.f,0.f,0.f,0.f};

  for (int ks=0; ks<16; ++ks) {
    const int dir = ks >> 3;
    const int kk0 = (ks & 7) * 32;
    const float* __restrict__ xzd = dir ? xzb : xzf;
    const float* __restrict__ Wod = dir ? Wob : Wof;
    if (ks) __syncthreads();
    // ---- stage A (gated y rows), XOR-granule layout
    {
      int rl = l0 + ar;
      size_t srow = (size_t)b*Ln + (dir ? (Ln-1-rl) : rl);
      const float* s = xzd + srow*512 + 256 + kk0 + kseg;
      short* ph = &Ah[amt*512 + arl*32];
      short* pl = &Al[amt*512 + arl*32];
      #pragma unroll
      for (int i=0;i<4;++i) {
        float4 v = *(const float4*)(s + 4*i);
        float vv[4] = {v.x,v.y,v.z,v.w};
        s4v hq, lq;
        #pragma unroll
        for (int e=0;e<4;++e) { short hh,ll; splitbf(vv[e],hh,ll); hq[e]=hh; lq[e]=ll; }
        int kl = kseg + 4*i;
        int off = (((kl>>3)^asw)<<3) + (kl&7);
        *(s4v*)(ph + off) = hq;
        *(s4v*)(pl + off) = lq;
      }
    }
    // ---- stage B (W_out): B[n][k] = W_out[kk0+k][n]
    {
      float4 vb[4];
      #pragma unroll
      for (int kk=0;kk<4;++kk)
        vb[kk] = *(const float4*)(Wod + (size_t)(kk0+kbase+kk)*128 + 4*q);
      #pragma unroll
      for (int e=0;e<4;++e) {
        int r = 4*q + e;
        int off = tile_off(r, g_true, ghalf);
        s4v hv, lv;
        #pragma unroll
        for (int kk=0;kk<4;++kk) {
          float f = ((const float*)&vb[kk])[e];
          short hh,ll; splitbf(f,hh,ll);
          hv[kk]=hh; lv[kk]=ll;
        }
        *(s4v*)&Bh[off] = hv;
        *(s4v*)&Bl[off] = lv;
      }
    }
    __syncthreads();
    // ---- fragment loads (plain b128) ----
    const int gsh = ((kg ^ ((r16>>1)&3)) << 3);
    s8v fah[4], fal[4], fbh[4], fbl[4];
    #pragma unroll
    for (int m=0;m<4;++m) {
      int idx = (wr*4+m)*512 + r16*32 + gsh;
      fah[m] = *(const s8v*)&Ah[idx];
      fal[m] = *(const s8v*)&Al[idx];
    }
    #pragma unroll
    for (int n=0;n<4;++n) {
      int idx = (wc*4+n)*512 + r16*32 + gsh;
      fbh[n] = *(const s8v*)&Bh[idx];
      fbl[n] = *(const s8v*)&Bl[idx];
    }
    #pragma unroll
    for (int m=0;m<4;++m)
      #pragma unroll
      for (int n=0;n<4;++n) {
        acc[m][n] = __builtin_amdgcn_mfma_f32_16x16x32_bf16(fah[m], fbh[n], acc[m][n], 0,0,0);
        acc[m][n] = __builtin_amdgcn_mfma_f32_16x16x32_bf16(fah[m], fbl[n], acc[m][n], 0,0,0);
        acc[m][n] = __builtin_amdgcn_mfma_f32_16x16x32_bf16(fal[m], fbh[n], acc[m][n], 0,0,0);
      }
  }
  #pragma unroll
  for (int m=0;m<4;++m)
    #pragma unroll
    for (int v=0;v<4;++v) {
      int row = row0 + wr*64 + m*16 + kg*4 + v;
      float* p = ysum + (size_t)row*128 + wc*64 + r16;
      #pragma unroll
      for (int n=0;n<4;++n) p[n*16] = acc[m][n][v];
    }
}

// ---------------- GroupNorm stats (partials) ----------------
__global__ __launch_bounds__(256) void k_gnstat(const float* __restrict__ ysum, float* __restrict__ part)
{
  const int bg = blockIdx.x >> 4;
  const int blk = blockIdx.x & 15;
  const int b = bg >> 2, g = bg & 3;
  float s=0.f, q=0.f;
  #pragma unroll
  for (int i=0;i<8;++i) {
    int e4 = blk*2048 + threadIdx.x + i*256;
    int l = e4 >> 3, c4 = e4 & 7;
    float4 v = *(const float4*)(ysum + (size_t)(b*Ln + l)*128 + g*32 + c4*4);
    s += v.x+v.y+v.z+v.w;
    q = fmaf(v.x,v.x, fmaf(v.y,v.y, fmaf(v.z,v.z, fmaf(v.w,v.w, q))));
  }
  __shared__ float rs[256], rq[256];
  rs[threadIdx.x]=s; rq[threadIdx.x]=q;
  __syncthreads();
  for (int off=128; off>0; off>>=1) {
    if (threadIdx.x < off) { rs[threadIdx.x]+=rs[threadIdx.x+off]; rq[threadIdx.x]+=rq[threadIdx.x+off]; }
    __syncthreads();
  }
  if (threadIdx.x==0) { part[blockIdx.x*2]=rs[0]; part[blockIdx.x*2+1]=rq[0]; }
}

__global__ void k_gnred(const float* __restrict__ part, float* __restrict__ mr)
{
  int t = threadIdx.x;
  if (t < 16) {
    float s=0.f,q=0.f;
    for (int k=0;k<16;++k){ s+=part[(t*16+k)*2]; q+=part[(t*16+k)*2+1]; }
    const float inv = 1.f/131072.f;
    float mean = s*inv;
    float var = fmaf(-mean, mean, q*inv);
    mr[t*2] = mean;
    mr[t*2+1] = rsqrtf(var + 1e-5f);
  }
}

// ---------------- GN apply + silu + residual ----------------
__global__ __launch_bounds__(256) void k_gnapply(const float* __restrict__ ysum,
    const float* __restrict__ mr, const float* __restrict__ gamma, const float* __restrict__ beta,
    const float* __restrict__ x, float* __restrict__ out)
{
  const int b = blockIdx.x >> 6;
  const int l0 = (blockIdx.x & 63) * 64;
  __shared__ float T[64][132];
  const int tid = threadIdx.x;
  #pragma unroll
  for (int j=0;j<8;++j) {
    int f = tid + j*256;
    int l = f >> 5, c4 = f & 31;
    *(float4*)&T[l][c4*4] = *(const float4*)(ysum + (size_t)(b*Ln + l0 + l)*128 + c4*4);
  }
  __syncthreads();
  #pragma unroll
  for (int j=0;j<8;++j) {
    int f = tid + j*256;
    int c = f >> 4, lv = f & 15;
    int bg = b*4 + (c>>5);
    float mean = mr[bg*2];
    float rstd = mr[bg*2+1];
    float gam = gamma[c], bet = beta[c];
    size_t base = (size_t)(b*Cn + c)*Ln + l0 + lv*4;
    float4 xv = *(const float4*)(x + base);
    float4 r;
    r.x = siluf(fmaf((T[lv*4+0][c]-mean)*rstd, gam, bet)) + xv.x;
    r.y = siluf(fmaf((T[lv*4+1][c]-mean)*rstd, gam, bet)) + xv.y;
    r.z = siluf(fmaf((T[lv*4+2][c]-mean)*rstd, gam, bet)) + xv.z;
    r.w = siluf(fmaf((T[lv*4+3][c]-mean)*rstd, gam, bet)) + xv.w;
    *(float4*)(out + base) = r;
  }
}

extern "C" void kernel_launch(void* const* d_in, const int* in_sizes, int n_in,
                              void* d_out, int out_size, void* d_ws, size_t ws_size,
                              hipStream_t stream) {
  const float* x      = (const float*)d_in[0];
  const float* W_in_f = (const float*)d_in[1];
  const float* cw_f   = (const float*)d_in[2];
  const float* cb_f   = (const float*)d_in[3];
  const float* Wx_f   = (const float*)d_in[4];
  const float* Wdt_f  = (const float*)d_in[5];
  const float* bdt_f  = (const float*)d_in[6];
  const float* Al_f   = (const float*)d_in[7];
  const float* D_f    = (const float*)d_in[8];
  const float* Wo_f   = (const float*)d_in[9];
  const float* W_in_b = (const float*)d_in[10];
  const float* cw_b   = (const float*)d_in[11];
  const float* cb_b   = (const float*)d_in[12];
  const float* Wx_b   = (const float*)d_in[13];
  const float* Wdt_b  = (const float*)d_in[14];
  const float* bdt_b  = (const float*)d_in[15];
  const float* Al_b   = (const float*)d_in[16];
  const float* D_b    = (const float*)d_in[17];
  const float* Wo_b   = (const float*)d_in[18];
  const float* gamma  = (const float*)d_in[19];
  const float* beta   = (const float*)d_in[20];
  float* out = (float*)d_out;

  float* w = (float*)d_ws;
  size_t o = 0;
  float* xz0  = w + o; o += (size_t)ROWS*512;
  float* xz1  = w + o; o += (size_t)ROWS*512;
  float* xc0  = w + o; o += (size_t)ROWS*256;
  float* xc1  = w + o; o += (size_t)ROWS*256;
  float* xdb0 = w + o; o += (size_t)ROWS*40;
  float* xdb1 = w + o; o += (size_t)ROWS*40;
  float* sdt0 = w + o; o += (size_t)Bn*NCn*256;
  float* sdt1 = w + o; o += (size_t)Bn*NCn*256;
  float* hk0  = w + o; o += (size_t)Bn*NCn*16*256;
  float* hk1  = w + o; o += (size_t)Bn*NCn*16*256;
  float* ysum = w + o; o += (size_t)ROWS*128;
  float* part = w + o; o += 512;
  float* mr   = w + o; o += 32;
  if (ws_size < o*sizeof(float)) return;

  k_g1<<<dim3(ROWS/128, 4, 2), 256, 0, stream>>>(x, W_in_f, W_in_b, xz0, xz1);
  k_conv<<<dim3(1024, 2), 256, 0, stream>>>(xz0, xz1, cw_f, cw_b, cb_f, cb_b, xc0, xc1);
  k_g2<<<dim3(ROWS/128, 1, 2), 256, 0, stream>>>(xc0, xc1, Wx_f, Wx_b, xdb0, xdb1);
  k_pass1<<<dim3(Bn*NCn, 2), 256, 0, stream>>>(xdb0, xdb1, xc0, xc1, Wdt_f, Wdt_b,
                                               bdt_f, bdt_b, Al_f, Al_b, sdt0, sdt1, hk0, hk1);
  k_pass2<<<dim3(64, 2), 256, 0, stream>>>(Al_f, Al_b, sdt0, sdt1, hk0, hk1);
  k_pass3<<<dim3(Bn*NCn, 2), 256, 0, stream>>>(xdb0, xdb1, xc0, xc1, Wdt_f, Wdt_b,
                                               bdt_f, bdt_b, Al_f, Al_b, D_f, D_b,
                                               hk0, hk1, xz0, xz1);
  k_gout<<<dim3(ROWS/128), 256, 0, stream>>>(xz0, xz1, Wo_f, Wo_b, ysum);
  k_gnstat<<<dim3(256), 256, 0, stream>>>(ysum, part);
  k_gnred<<<dim3(1), 64, 0, stream>>>(part, mr);
  k_gnapply<<<dim3(256), 256, 0, stream>>>(ysum, mr, gamma, beta, x, out);
}